// Round 1
// baseline (316.013 us; speedup 1.0000x reference)
//
#include <hip/hip_runtime.h>
#include <math.h>

#define BB 1024
#define VV 50257
#define EE 128
#define TN 64
#define NVT ((VV + TN - 1) / TN)   /* 786 */

typedef __bf16 bf16x8 __attribute__((ext_vector_type(8)));
typedef float f32x4 __attribute__((ext_vector_type(4)));

static __device__ __forceinline__ unsigned short f2bf(float f) {
  unsigned int u = __float_as_uint(f);
  u += 0x7fffu + ((u >> 16) & 1u);
  return (unsigned short)(u >> 16);
}

// K1: find the one-hot index (and value) per row. xs is [BB][VV] f32, flat-divisible by 4.
__global__ void k_scan(const float* __restrict__ xs, int* __restrict__ idx,
                       float* __restrict__ vals) {
  const long total4 = (long)BB * VV / 4;
  const long stride = (long)gridDim.x * blockDim.x;
  for (long i = (long)blockIdx.x * blockDim.x + threadIdx.x; i < total4; i += stride) {
    float4 v = ((const float4*)xs)[i];
    if (v.x != 0.f || v.y != 0.f || v.z != 0.f || v.w != 0.f) {
      float vv[4] = {v.x, v.y, v.z, v.w};
#pragma unroll
      for (int c = 0; c < 4; c++) {
        if (vv[c] != 0.f) {
          long f = i * 4 + c;
          int b = (int)(f / VV);
          int p = (int)(f - (long)b * VV);
          idx[b] = p;
          vals[b] = vv[c];
        }
      }
    }
  }
}

// K2: EMBEDM f32 -> bf16 copy.
__global__ void k_cvt(const float* __restrict__ em, unsigned short* __restrict__ ebf) {
  const int total4 = VV * EE / 4;
  const int stride = gridDim.x * blockDim.x;
  for (int i = blockIdx.x * blockDim.x + threadIdx.x; i < total4; i += stride) {
    float4 v = ((const float4*)em)[i];
    ushort4 o;
    o.x = f2bf(v.x); o.y = f2bf(v.y); o.z = f2bf(v.z); o.w = f2bf(v.w);
    ((ushort4*)ebf)[i] = o;
  }
}

// K3: y[b] = (val * EMBEDM[idx[b]]) @ metric, stored bf16. One block (128 thr) per row.
__global__ void k_embed(const float* __restrict__ em, const float* __restrict__ metric,
                        const int* __restrict__ idx, const float* __restrict__ vals,
                        unsigned short* __restrict__ ybf) {
  __shared__ float x[EE];
  const int b = blockIdx.x;
  const int e = threadIdx.x;
  const int row = idx[b];
  const float val = vals[b];
  x[e] = em[(long)row * EE + e] * val;
  __syncthreads();
  float acc = 0.f;
#pragma unroll
  for (int k = 0; k < EE; k++) acc = fmaf(x[k], metric[k * EE + e], acc);
  ybf[b * EE + e] = f2bf(acc);
}

// K4/K6: tiled MFMA GEMM scores = Y @ E^T. Block = 4 waves, tile 64 rows x 64 cols.
// PASS_B=false: emit per-(row, vtile) partial max & sumexp.
// PASS_B=true : out[row][col] = score - lse[row].
template <bool PASS_B>
__global__ __launch_bounds__(256) void k_gemm(const unsigned short* __restrict__ ybf,
                                              const unsigned short* __restrict__ ebf,
                                              float* __restrict__ pm, float* __restrict__ ps,
                                              const float* __restrict__ lse,
                                              float* __restrict__ out) {
  const int vt = blockIdx.x;                 // 0..NVT-1
  const int rb = blockIdx.y;                 // 0..15
  const int w = threadIdx.x >> 6;            // wave 0..3
  const int l = threadIdx.x & 63;
  const int g = l >> 4;                      // 16-lane group 0..3
  const int li = l & 15;
  const int rowbase = rb * 64 + w * 16;      // this wave's 16 rows
  const int colbase = vt * TN;

  // A fragments: lane li -> row (rowbase+li), k = kk*32 + g*8 + 0..7 (contiguous bf16x8)
  bf16x8 a[4];
  const bf16x8* yv = (const bf16x8*)(ybf + (size_t)(rowbase + li) * EE);
#pragma unroll
  for (int kk = 0; kk < 4; kk++) a[kk] = yv[kk * 4 + g];

  f32x4 acc[4];
#pragma unroll
  for (int ns = 0; ns < 4; ns++) acc[ns] = (f32x4){0.f, 0.f, 0.f, 0.f};

#pragma unroll
  for (int ns = 0; ns < 4; ns++) {
    const int c = colbase + ns * 16 + li;
    const int cc = c < VV ? c : VV - 1;      // clamp; masked later
    const bf16x8* ev = (const bf16x8*)(ebf + (size_t)cc * EE);
#pragma unroll
    for (int kk = 0; kk < 4; kk++) {
      bf16x8 bfrag = ev[kk * 4 + g];
      acc[ns] = __builtin_amdgcn_mfma_f32_16x16x32_bf16(a[kk], bfrag, acc[ns], 0, 0, 0);
    }
  }

  if (!PASS_B) {
    bool valid[4];
#pragma unroll
    for (int ns = 0; ns < 4; ns++) valid[ns] = (colbase + ns * 16 + li) < VV;

    float mj[4], sj[4];
#pragma unroll
    for (int j = 0; j < 4; j++) {
      float m = -INFINITY;
#pragma unroll
      for (int ns = 0; ns < 4; ns++)
        if (valid[ns]) m = fmaxf(m, acc[ns][j]);
      mj[j] = m;
    }
#pragma unroll
    for (int off = 8; off; off >>= 1) {
#pragma unroll
      for (int j = 0; j < 4; j++) mj[j] = fmaxf(mj[j], __shfl_xor(mj[j], off));
    }
#pragma unroll
    for (int j = 0; j < 4; j++) {
      float s = 0.f;
#pragma unroll
      for (int ns = 0; ns < 4; ns++)
        if (valid[ns]) s += __expf(acc[ns][j] - mj[j]);
      sj[j] = s;
    }
#pragma unroll
    for (int off = 8; off; off >>= 1) {
#pragma unroll
      for (int j = 0; j < 4; j++) sj[j] += __shfl_xor(sj[j], off);
    }
    if (li == 0) {
#pragma unroll
      for (int j = 0; j < 4; j++) {
        const int row = rowbase + g * 4 + j;
        pm[(size_t)row * NVT + vt] = mj[j];
        ps[(size_t)row * NVT + vt] = sj[j];
      }
    }
  } else {
    float L[4];
#pragma unroll
    for (int j = 0; j < 4; j++) L[j] = lse[rowbase + g * 4 + j];
#pragma unroll
    for (int ns = 0; ns < 4; ns++) {
      const int c = colbase + ns * 16 + li;
      if (c < VV) {
#pragma unroll
        for (int j = 0; j < 4; j++) {
          const int row = rowbase + g * 4 + j;
          out[(size_t)row * VV + c] = acc[ns][j] - L[j];
        }
      }
    }
  }
}

// K5: combine per-tile partials into lse per row. One block (256 thr) per row.
__global__ void k_lse(const float* __restrict__ pm, const float* __restrict__ ps,
                      float* __restrict__ lse) {
  const int row = blockIdx.x;
  const int t = threadIdx.x;
  __shared__ float sm[4];
  __shared__ float ssum[4];

  float m = -INFINITY;
  for (int i = t; i < NVT; i += 256) m = fmaxf(m, pm[(size_t)row * NVT + i]);
#pragma unroll
  for (int off = 32; off; off >>= 1) m = fmaxf(m, __shfl_xor(m, off));
  if ((t & 63) == 0) sm[t >> 6] = m;
  __syncthreads();
  m = fmaxf(fmaxf(sm[0], sm[1]), fmaxf(sm[2], sm[3]));

  float s = 0.f;
  for (int i = t; i < NVT; i += 256)
    s += ps[(size_t)row * NVT + i] * __expf(pm[(size_t)row * NVT + i] - m);
#pragma unroll
  for (int off = 32; off; off >>= 1) s += __shfl_xor(s, off);
  if ((t & 63) == 0) ssum[t >> 6] = s;
  __syncthreads();
  if (t == 0) lse[row] = m + logf(ssum[0] + ssum[1] + ssum[2] + ssum[3]);
}

extern "C" void kernel_launch(void* const* d_in, const int* in_sizes, int n_in,
                              void* d_out, int out_size, void* d_ws, size_t ws_size,
                              hipStream_t stream) {
  const float* xs = (const float*)d_in[0];
  const float* em = (const float*)d_in[1];
  const float* metric = (const float*)d_in[2];
  float* out = (float*)d_out;

  char* w = (char*)d_ws;
  int* idx = (int*)(w + 0);                                   // 4 KB
  float* vals = (float*)(w + 4096);                           // 4 KB
  float* lse = (float*)(w + 8192);                            // 4 KB
  unsigned short* ybf = (unsigned short*)(w + 12288);         // 256 KB
  unsigned short* ebf = (unsigned short*)(w + 12288 + 262144);                 // 12.87 MB
  float* pm = (float*)(w + 12288 + 262144 + 12865792);                         // 3.22 MB
  float* ps = (float*)(w + 12288 + 262144 + 12865792 + (size_t)BB * NVT * 4);  // 3.22 MB

  k_scan<<<2048, 256, 0, stream>>>(xs, idx, vals);
  k_cvt<<<2048, 256, 0, stream>>>(em, ebf);
  k_embed<<<BB, EE, 0, stream>>>(em, metric, idx, vals, ybf);
  k_gemm<false><<<dim3(NVT, 16), 256, 0, stream>>>(ybf, ebf, pm, ps, nullptr, nullptr);
  k_lse<<<BB, 256, 0, stream>>>(pm, ps, lse);
  k_gemm<true><<<dim3(NVT, 16), 256, 0, stream>>>(ybf, ebf, nullptr, nullptr, lse, out);
}

// Round 2
// 202.766 us; speedup vs baseline: 1.5585x; 1.5585x over previous
//
#include <hip/hip_runtime.h>
#include <math.h>

#define BB 1024
#define VV 50257
#define EE 128
#define TN 64
#define NVT ((VV + TN - 1) / TN)   /* 786 */

typedef __bf16 bf16x8 __attribute__((ext_vector_type(8)));
typedef float f32x4 __attribute__((ext_vector_type(4)));

static __device__ __forceinline__ unsigned short f2bf(float f) {
  unsigned int u = __float_as_uint(f);
  u += 0x7fffu + ((u >> 16) & 1u);
  return (unsigned short)(u >> 16);
}

// K1: find the one-hot index (and value) per row. xs is [BB][VV] f32, flat-divisible by 4.
__global__ void k_scan(const float* __restrict__ xs, int* __restrict__ idx,
                       float* __restrict__ vals) {
  const long total4 = (long)BB * VV / 4;
  const long stride = (long)gridDim.x * blockDim.x;
  for (long i = (long)blockIdx.x * blockDim.x + threadIdx.x; i < total4; i += stride) {
    float4 v = ((const float4*)xs)[i];
    if (v.x != 0.f || v.y != 0.f || v.z != 0.f || v.w != 0.f) {
      float vv[4] = {v.x, v.y, v.z, v.w};
#pragma unroll
      for (int c = 0; c < 4; c++) {
        if (vv[c] != 0.f) {
          long f = i * 4 + c;
          int b = (int)(f / VV);
          int p = (int)(f - (long)b * VV);
          idx[b] = p;
          vals[b] = vv[c];
        }
      }
    }
  }
}

// K2: EMBEDM f32 -> bf16 copy.
__global__ void k_cvt(const float* __restrict__ em, unsigned short* __restrict__ ebf) {
  const int total4 = VV * EE / 4;
  const int stride = gridDim.x * blockDim.x;
  for (int i = blockIdx.x * blockDim.x + threadIdx.x; i < total4; i += stride) {
    float4 v = ((const float4*)em)[i];
    ushort4 o;
    o.x = f2bf(v.x); o.y = f2bf(v.y); o.z = f2bf(v.z); o.w = f2bf(v.w);
    ((ushort4*)ebf)[i] = o;
  }
}

// K3: y[b] = (val * EMBEDM[idx[b]]) @ metric, stored bf16. One block (128 thr) per row.
__global__ void k_embed(const float* __restrict__ em, const float* __restrict__ metric,
                        const int* __restrict__ idx, const float* __restrict__ vals,
                        unsigned short* __restrict__ ybf) {
  __shared__ float x[EE];
  const int b = blockIdx.x;
  const int e = threadIdx.x;
  const int row = idx[b];
  const float val = vals[b];
  x[e] = em[(long)row * EE + e] * val;
  __syncthreads();
  float acc = 0.f;
#pragma unroll
  for (int k = 0; k < EE; k++) acc = fmaf(x[k], metric[k * EE + e], acc);
  ybf[b * EE + e] = f2bf(acc);
}

// K4/K6: tiled MFMA GEMM scores = Y @ E^T.
// Block = 4 waves. Each block owns one 64-col tile (B-frags held in registers
// for the whole block) and 512 rows (8 row-blocks of 64, wave w doing 16 rows each).
// PASS_B=false: emit per-(row, vtile) partial max & sumexp.
// PASS_B=true : out[row][col] = score - lse[row].
template <bool PASS_B>
__global__ __launch_bounds__(256) void k_gemm(const unsigned short* __restrict__ ybf,
                                              const unsigned short* __restrict__ ebf,
                                              float* __restrict__ pm, float* __restrict__ ps,
                                              const float* __restrict__ lse,
                                              float* __restrict__ out) {
  const int vt = blockIdx.x;                 // 0..NVT-1
  const int half = blockIdx.y;               // 0..1 (rows half*512 ..)
  const int w = threadIdx.x >> 6;            // wave 0..3
  const int l = threadIdx.x & 63;
  const int g = l >> 4;                      // 16-lane group 0..3
  const int li = l & 15;
  const int colbase = vt * TN;

  // B fragments: held in registers for the entire block. [ns][kk]
  bool valid[4];
  bf16x8 bfr[4][4];
#pragma unroll
  for (int ns = 0; ns < 4; ns++) {
    const int c = colbase + ns * 16 + li;
    valid[ns] = c < VV;
    const int cc = valid[ns] ? c : VV - 1;   // clamp; masked in epilogue
    const bf16x8* ev = (const bf16x8*)(ebf + (size_t)cc * EE);
#pragma unroll
    for (int kk = 0; kk < 4; kk++) bfr[ns][kk] = ev[kk * 4 + g];
  }

#pragma unroll 2
  for (int rb = 0; rb < 8; rb++) {
    const int rowbase = half * 512 + rb * 64 + w * 16;   // this wave's 16 rows

    // A fragments: lane li -> row (rowbase+li), k = kk*32 + g*8 + 0..7
    bf16x8 a[4];
    const bf16x8* yv = (const bf16x8*)(ybf + (size_t)(rowbase + li) * EE);
#pragma unroll
    for (int kk = 0; kk < 4; kk++) a[kk] = yv[kk * 4 + g];

    f32x4 acc[4];
#pragma unroll
    for (int ns = 0; ns < 4; ns++) acc[ns] = (f32x4){0.f, 0.f, 0.f, 0.f};
#pragma unroll
    for (int ns = 0; ns < 4; ns++)
#pragma unroll
      for (int kk = 0; kk < 4; kk++)
        acc[ns] = __builtin_amdgcn_mfma_f32_16x16x32_bf16(a[kk], bfr[ns][kk], acc[ns], 0, 0, 0);

    if (!PASS_B) {
      float mj[4], sj[4];
#pragma unroll
      for (int j = 0; j < 4; j++) {
        float m = -INFINITY;
#pragma unroll
        for (int ns = 0; ns < 4; ns++)
          if (valid[ns]) m = fmaxf(m, acc[ns][j]);
        mj[j] = m;
      }
#pragma unroll
      for (int off = 8; off; off >>= 1) {
#pragma unroll
        for (int j = 0; j < 4; j++) mj[j] = fmaxf(mj[j], __shfl_xor(mj[j], off));
      }
#pragma unroll
      for (int j = 0; j < 4; j++) {
        float s = 0.f;
#pragma unroll
        for (int ns = 0; ns < 4; ns++)
          if (valid[ns]) s += __expf(acc[ns][j] - mj[j]);
        sj[j] = s;
      }
#pragma unroll
      for (int off = 8; off; off >>= 1) {
#pragma unroll
        for (int j = 0; j < 4; j++) sj[j] += __shfl_xor(sj[j], off);
      }
      if (li == 0) {
#pragma unroll
        for (int j = 0; j < 4; j++) {
          const int row = rowbase + g * 4 + j;
          pm[(size_t)row * NVT + vt] = mj[j];
          ps[(size_t)row * NVT + vt] = sj[j];
        }
      }
    } else {
      float L[4];
#pragma unroll
      for (int j = 0; j < 4; j++) L[j] = lse[rowbase + g * 4 + j];
#pragma unroll
      for (int ns = 0; ns < 4; ns++) {
        const int c = colbase + ns * 16 + li;
        if (c < VV) {
#pragma unroll
          for (int j = 0; j < 4; j++) {
            const int row = rowbase + g * 4 + j;
            out[(size_t)row * VV + c] = acc[ns][j] - L[j];
          }
        }
      }
    }
  }
}

// K5: combine per-tile partials into lse per row. One block (256 thr) per row.
__global__ void k_lse(const float* __restrict__ pm, const float* __restrict__ ps,
                      float* __restrict__ lse) {
  const int row = blockIdx.x;
  const int t = threadIdx.x;
  __shared__ float sm[4];
  __shared__ float ssum[4];

  float m = -INFINITY;
  for (int i = t; i < NVT; i += 256) m = fmaxf(m, pm[(size_t)row * NVT + i]);
#pragma unroll
  for (int off = 32; off; off >>= 1) m = fmaxf(m, __shfl_xor(m, off));
  if ((t & 63) == 0) sm[t >> 6] = m;
  __syncthreads();
  m = fmaxf(fmaxf(sm[0], sm[1]), fmaxf(sm[2], sm[3]));

  float s = 0.f;
  for (int i = t; i < NVT; i += 256)
    s += ps[(size_t)row * NVT + i] * __expf(pm[(size_t)row * NVT + i] - m);
#pragma unroll
  for (int off = 32; off; off >>= 1) s += __shfl_xor(s, off);
  if ((t & 63) == 0) ssum[t >> 6] = s;
  __syncthreads();
  if (t == 0) lse[row] = m + logf(ssum[0] + ssum[1] + ssum[2] + ssum[3]);
}

extern "C" void kernel_launch(void* const* d_in, const int* in_sizes, int n_in,
                              void* d_out, int out_size, void* d_ws, size_t ws_size,
                              hipStream_t stream) {
  const float* xs = (const float*)d_in[0];
  const float* em = (const float*)d_in[1];
  const float* metric = (const float*)d_in[2];
  float* out = (float*)d_out;

  char* w = (char*)d_ws;
  int* idx = (int*)(w + 0);                                   // 4 KB
  float* vals = (float*)(w + 4096);                           // 4 KB
  float* lse = (float*)(w + 8192);                            // 4 KB
  unsigned short* ybf = (unsigned short*)(w + 12288);         // 256 KB
  unsigned short* ebf = (unsigned short*)(w + 12288 + 262144);                 // 12.87 MB
  float* pm = (float*)(w + 12288 + 262144 + 12865792);                         // 3.22 MB
  float* ps = (float*)(w + 12288 + 262144 + 12865792 + (size_t)BB * NVT * 4);  // 3.22 MB

  k_scan<<<2048, 256, 0, stream>>>(xs, idx, vals);
  k_cvt<<<2048, 256, 0, stream>>>(em, ebf);
  k_embed<<<BB, EE, 0, stream>>>(em, metric, idx, vals, ybf);
  k_gemm<false><<<dim3(NVT, 2), 256, 0, stream>>>(ybf, ebf, pm, ps, nullptr, nullptr);
  k_lse<<<BB, 256, 0, stream>>>(pm, ps, lse);
  k_gemm<true><<<dim3(NVT, 2), 256, 0, stream>>>(ybf, ebf, nullptr, nullptr, lse, out);
}

// Round 3
// 201.601 us; speedup vs baseline: 1.5675x; 1.0058x over previous
//
#include <hip/hip_runtime.h>
#include <math.h>

#define BB 1024
#define VV 50257
#define EE 128
#define TN 64
#define NVT ((VV + TN - 1) / TN)   /* 786 */

typedef __bf16 bf16x8 __attribute__((ext_vector_type(8)));
typedef float f32x4 __attribute__((ext_vector_type(4)));
typedef f32x4 __attribute__((aligned(4))) f32x4u;   // 4B-aligned vector store (VV odd)

static __device__ __forceinline__ unsigned short f2bf(float f) {
  unsigned int u = __float_as_uint(f);
  u += 0x7fffu + ((u >> 16) & 1u);
  return (unsigned short)(u >> 16);
}

// K1: find the one-hot index (and value) per row. xs is [BB][VV] f32, flat-divisible by 4.
__global__ void k_scan(const float* __restrict__ xs, int* __restrict__ idx,
                       float* __restrict__ vals) {
  const long total4 = (long)BB * VV / 4;
  const long stride = (long)gridDim.x * blockDim.x;
  for (long i = (long)blockIdx.x * blockDim.x + threadIdx.x; i < total4; i += stride) {
    float4 v = ((const float4*)xs)[i];
    if (v.x != 0.f || v.y != 0.f || v.z != 0.f || v.w != 0.f) {
      float vv[4] = {v.x, v.y, v.z, v.w};
#pragma unroll
      for (int c = 0; c < 4; c++) {
        if (vv[c] != 0.f) {
          long f = i * 4 + c;
          int b = (int)(f / VV);
          int p = (int)(f - (long)b * VV);
          idx[b] = p;
          vals[b] = vv[c];
        }
      }
    }
  }
}

// K2: EMBEDM f32 -> bf16 copy.
__global__ void k_cvt(const float* __restrict__ em, unsigned short* __restrict__ ebf) {
  const int total4 = VV * EE / 4;
  const int stride = gridDim.x * blockDim.x;
  for (int i = blockIdx.x * blockDim.x + threadIdx.x; i < total4; i += stride) {
    float4 v = ((const float4*)em)[i];
    ushort4 o;
    o.x = f2bf(v.x); o.y = f2bf(v.y); o.z = f2bf(v.z); o.w = f2bf(v.w);
    ((ushort4*)ebf)[i] = o;
  }
}

// K3: y[b] = (val * EMBEDM[idx[b]]) @ metric, stored bf16. One block (128 thr) per row.
__global__ void k_embed(const float* __restrict__ em, const float* __restrict__ metric,
                        const int* __restrict__ idx, const float* __restrict__ vals,
                        unsigned short* __restrict__ ybf) {
  __shared__ float x[EE];
  const int b = blockIdx.x;
  const int e = threadIdx.x;
  const int row = idx[b];
  const float val = vals[b];
  x[e] = em[(long)row * EE + e] * val;
  __syncthreads();
  float acc = 0.f;
#pragma unroll
  for (int k = 0; k < EE; k++) acc = fmaf(x[k], metric[k * EE + e], acc);
  ybf[b * EE + e] = f2bf(acc);
}

// ---- GEMM scores = Y @ E^T, swapped-operand MFMA (A = E tile -> M = vocab,
// B = Y rows -> N = batch). D layout: batch row = lane&15, vocab col =
// colbase + ns*16 + (lane>>4)*4 + reg. Each lane owns ONE batch row and 16
// vocab cols -> cheap row reduction (pass A) and float4 stores (pass B).

static __device__ __forceinline__ void loadY(bf16x8 (&y)[4], const unsigned short* __restrict__ ybf,
                                             int row, int g) {
  const bf16x8* yv = (const bf16x8*)(ybf + (size_t)row * EE);
#pragma unroll
  for (int kk = 0; kk < 4; kk++) y[kk] = yv[kk * 4 + g];
}

template <bool PASS_B>
static __device__ __forceinline__ void process_rb(const bf16x8 (&afr)[4][4], const bf16x8 (&y)[4],
                                                  int rowbase, int vt, int li, int g, int l,
                                                  int vbase_l,
                                                  float* __restrict__ pm, float* __restrict__ ps,
                                                  const float* __restrict__ lse,
                                                  float* __restrict__ out) {
  f32x4 acc[4];
#pragma unroll
  for (int ns = 0; ns < 4; ns++) acc[ns] = (f32x4){0.f, 0.f, 0.f, 0.f};
#pragma unroll
  for (int ns = 0; ns < 4; ns++)
#pragma unroll
    for (int kk = 0; kk < 4; kk++)
      acc[ns] = __builtin_amdgcn_mfma_f32_16x16x32_bf16(afr[ns][kk], y[kk], acc[ns], 0, 0, 0);

  const int row = rowbase + li;

  if (!PASS_B) {
    float m = -INFINITY;
#pragma unroll
    for (int ns = 0; ns < 4; ns++)
#pragma unroll
      for (int r = 0; r < 4; r++)
        if (vbase_l + ns * 16 + r < VV) m = fmaxf(m, acc[ns][r]);
    m = fmaxf(m, __shfl_xor(m, 16));
    m = fmaxf(m, __shfl_xor(m, 32));
    float s = 0.f;
#pragma unroll
    for (int ns = 0; ns < 4; ns++)
#pragma unroll
      for (int r = 0; r < 4; r++)
        if (vbase_l + ns * 16 + r < VV) s += __expf(acc[ns][r] - m);
    s += __shfl_xor(s, 16);
    s += __shfl_xor(s, 32);
    if (l < 16) {
      pm[(size_t)row * NVT + vt] = m;
      ps[(size_t)row * NVT + vt] = s;
    }
  } else {
    const float L = lse[row];
    float* orow = out + (size_t)row * VV;
#pragma unroll
    for (int ns = 0; ns < 4; ns++) {
      const int c = vbase_l + ns * 16;
      if (c + 3 < VV) {
        f32x4 v;
#pragma unroll
        for (int r = 0; r < 4; r++) v[r] = acc[ns][r] - L;
        *(f32x4u*)(orow + c) = v;
      } else {
#pragma unroll
        for (int r = 0; r < 4; r++)
          if (c + r < VV) orow[c + r] = acc[ns][r] - L;
      }
    }
  }
}

template <bool PASS_B>
static __device__ __forceinline__ void gemm_body(const unsigned short* __restrict__ ybf,
                                                 const unsigned short* __restrict__ ebf,
                                                 float* __restrict__ pm, float* __restrict__ ps,
                                                 const float* __restrict__ lse,
                                                 float* __restrict__ out) {
  const int vt = blockIdx.x;                 // 0..NVT-1
  const int half = blockIdx.y;               // 0..1
  const int w = threadIdx.x >> 6;            // wave 0..3
  const int l = threadIdx.x & 63;
  const int g = l >> 4;
  const int li = l & 15;
  const int colbase = vt * TN;
  const int vbase_l = colbase + g * 4;       // this lane's vocab col base (per ns: +ns*16)

  // A fragments (E rows = vocab cols of this tile), register-resident: [ns][kk]
  bf16x8 afr[4][4];
#pragma unroll
  for (int ns = 0; ns < 4; ns++) {
    const int c = colbase + ns * 16 + li;
    const int cc = c < VV ? c : VV - 1;      // clamp; masked in epilogue
    const bf16x8* ev = (const bf16x8*)(ebf + (size_t)cc * EE);
#pragma unroll
    for (int kk = 0; kk < 4; kk++) afr[ns][kk] = ev[kk * 4 + g];
  }

  const int rowstart = half * 512 + w * 16;  // wave's rows for rb: rowstart + rb*64 + 0..15

  bf16x8 yA[4], yB[4];
  loadY(yA, ybf, rowstart + 0 * 64 + li, g);
#pragma unroll
  for (int it = 0; it < 4; it++) {
    loadY(yB, ybf, rowstart + (2 * it + 1) * 64 + li, g);
    process_rb<PASS_B>(afr, yA, rowstart + (2 * it) * 64, vt, li, g, l, vbase_l, pm, ps, lse, out);
    if (it < 3) loadY(yA, ybf, rowstart + (2 * it + 2) * 64 + li, g);
    process_rb<PASS_B>(afr, yB, rowstart + (2 * it + 1) * 64, vt, li, g, l, vbase_l, pm, ps, lse, out);
  }
}

__global__ __launch_bounds__(256) void k_gemm_a(const unsigned short* __restrict__ ybf,
                                                const unsigned short* __restrict__ ebf,
                                                float* __restrict__ pm, float* __restrict__ ps) {
  gemm_body<false>(ybf, ebf, pm, ps, nullptr, nullptr);
}

__global__ __launch_bounds__(256) void k_gemm_b(const unsigned short* __restrict__ ybf,
                                                const unsigned short* __restrict__ ebf,
                                                const float* __restrict__ lse,
                                                float* __restrict__ out) {
  gemm_body<true>(ybf, ebf, nullptr, nullptr, lse, out);
}

// K5: combine per-tile partials into lse per row. One block (256 thr) per row.
__global__ void k_lse(const float* __restrict__ pm, const float* __restrict__ ps,
                      float* __restrict__ lse) {
  const int row = blockIdx.x;
  const int t = threadIdx.x;
  __shared__ float sm[4];
  __shared__ float ssum[4];

  float m = -INFINITY;
  for (int i = t; i < NVT; i += 256) m = fmaxf(m, pm[(size_t)row * NVT + i]);
#pragma unroll
  for (int off = 32; off; off >>= 1) m = fmaxf(m, __shfl_xor(m, off));
  if ((t & 63) == 0) sm[t >> 6] = m;
  __syncthreads();
  m = fmaxf(fmaxf(sm[0], sm[1]), fmaxf(sm[2], sm[3]));

  float s = 0.f;
  for (int i = t; i < NVT; i += 256)
    s += ps[(size_t)row * NVT + i] * __expf(pm[(size_t)row * NVT + i] - m);
#pragma unroll
  for (int off = 32; off; off >>= 1) s += __shfl_xor(s, off);
  if ((t & 63) == 0) ssum[t >> 6] = s;
  __syncthreads();
  if (t == 0) lse[row] = m + logf(ssum[0] + ssum[1] + ssum[2] + ssum[3]);
}

extern "C" void kernel_launch(void* const* d_in, const int* in_sizes, int n_in,
                              void* d_out, int out_size, void* d_ws, size_t ws_size,
                              hipStream_t stream) {
  const float* xs = (const float*)d_in[0];
  const float* em = (const float*)d_in[1];
  const float* metric = (const float*)d_in[2];
  float* out = (float*)d_out;

  char* w = (char*)d_ws;
  int* idx = (int*)(w + 0);                                   // 4 KB
  float* vals = (float*)(w + 4096);                           // 4 KB
  float* lse = (float*)(w + 8192);                            // 4 KB
  unsigned short* ybf = (unsigned short*)(w + 12288);         // 256 KB
  unsigned short* ebf = (unsigned short*)(w + 12288 + 262144);                 // 12.87 MB
  float* pm = (float*)(w + 12288 + 262144 + 12865792);                         // 3.22 MB
  float* ps = (float*)(w + 12288 + 262144 + 12865792 + (size_t)BB * NVT * 4);  // 3.22 MB

  k_scan<<<2048, 256, 0, stream>>>(xs, idx, vals);
  k_cvt<<<2048, 256, 0, stream>>>(em, ebf);
  k_embed<<<BB, EE, 0, stream>>>(em, metric, idx, vals, ybf);
  k_gemm_a<<<dim3(NVT, 2), 256, 0, stream>>>(ybf, ebf, pm, ps);
  k_lse<<<BB, 256, 0, stream>>>(pm, ps, lse);
  k_gemm_b<<<dim3(NVT, 2), 256, 0, stream>>>(ybf, ebf, lse, out);
}